// Round 8
// baseline (261.862 us; speedup 1.0000x reference)
//
#include <hip/hip_runtime.h>
#include <hip/hip_bf16.h>

// RGCN layer, input-space aggregation, NO LDS atomics:
//   counting-sort edges by key = dst*8+etype (scatter bumps off[] itself; post-
//   scatter off[k] = segment END). Fused kernel: each wave owns 2 dst rows'
//   contiguous edge range; DOUBLE-BUFFERED 16-edge gather pipeline (all 16 row
//   loads of batch b+1 forced in flight -- sched_barrier(0) -- while batch b is
//   consumed from registers), flush once per sorted run with a plain ds_write.
//   Then one MFMA GEMM K = 8*128+128 vs [W_0;..;W_7;root], bias+PReLU epilogue.

#define N_NODES 50000
#define N_EDGES 800000
#define N_REL   8
#define CH      128
#define KTOT    1152                       // 8*128 + 128 (root)
#define NSEG    (N_NODES * N_REL)          // 400000
#define DT      16                         // dst rows per fused block
#define SCAN_BLK 1024
#define NSCAN   ((NSEG + SCAN_BLK - 1) / SCAN_BLK)  // 391
#define BSTRIDE 1160                       // bf16 row stride; 2320B/16 = 145 ≡ 1 mod 8
#define WBLK    576                        // blocks for build_w part of k_prep

typedef __attribute__((ext_vector_type(8))) short bf16x8;
typedef __attribute__((ext_vector_type(4))) float f32x4;

// Merged: WcatT build (blocks [0,WBLK)) + x->bf16 convert (blocks [WBLK,..)).
__global__ void k_prep(const float* __restrict__ basis, const float* __restrict__ comp,
                       const float* __restrict__ root, __hip_bfloat16* __restrict__ WcatT,
                       const float* __restrict__ x, unsigned int* __restrict__ xb) {
  int b = blockIdx.x, tid = threadIdx.x;
  if (b < WBLK) {                          // WcatT[o][k], CH*KTOT = WBLK*256 exactly
    int idx = b * 256 + tid;
    int o = idx / KTOT, k = idx % KTOT;
    float v;
    if (k < N_REL * CH) {
      int r = k >> 7, i = k & (CH - 1);
      float acc = 0.f;
#pragma unroll
      for (int bb = 0; bb < 8; ++bb) acc += comp[r * 8 + bb] * basis[(bb * CH + i) * CH + o];
      v = acc;
    } else {
      v = root[(k - N_REL * CH) * CH + o];
    }
    WcatT[(size_t)o * KTOT + k] = __float2bfloat16(v);
  } else {                                 // xb: one thread = 4 channels
    int idx = (b - WBLK) * 256 + tid;      // N_NODES*CH/4 = 6250*256 exactly
    const float4 v = *reinterpret_cast<const float4*>(x + (size_t)idx * 4);
    __hip_bfloat16 h0 = __float2bfloat16(v.x), h1 = __float2bfloat16(v.y);
    __hip_bfloat16 h2 = __float2bfloat16(v.z), h3 = __float2bfloat16(v.w);
    xb[(size_t)idx * 2]     = *(unsigned short*)&h0 | ((unsigned int)*(unsigned short*)&h1 << 16);
    xb[(size_t)idx * 2 + 1] = *(unsigned short*)&h2 | ((unsigned int)*(unsigned short*)&h3 << 16);
  }
}

__global__ void k_hist(const int* __restrict__ dst, const int* __restrict__ et,
                       int* __restrict__ hist) {
  int e = blockIdx.x * 256 + threadIdx.x;
  if (e < N_EDGES) atomicAdd(&hist[dst[e] * N_REL + et[e]], 1);
}

__global__ void k_scan1(const int* __restrict__ hist, int* __restrict__ off,
                        int* __restrict__ bsum) {
  __shared__ int sd[256];
  int t = threadIdx.x, b = blockIdx.x;
  int base = b * SCAN_BLK + t * 4;
  int v[4]; int s = 0;
#pragma unroll
  for (int j = 0; j < 4; ++j) { int i = base + j; v[j] = (i < NSEG) ? hist[i] : 0; s += v[j]; }
  sd[t] = s; __syncthreads();
  for (int o = 1; o < 256; o <<= 1) {
    int add = (t >= o) ? sd[t - o] : 0; __syncthreads();
    sd[t] += add; __syncthreads();
  }
  int excl = sd[t] - s;
  int run = excl;
#pragma unroll
  for (int j = 0; j < 4; ++j) { int i = base + j; if (i < NSEG) off[i] = run; run += v[j]; }
  if (t == 255) bsum[b] = sd[255];
}

__global__ void k_scan2(int* __restrict__ bsum) {
  __shared__ int sd[512];
  int t = threadIdx.x;
  int v = (t < NSCAN) ? bsum[t] : 0;
  sd[t] = v; __syncthreads();
  for (int o = 1; o < 512; o <<= 1) {
    int add = (t >= o) ? sd[t - o] : 0; __syncthreads();
    sd[t] += add; __syncthreads();
  }
  int excl = (t == 0) ? 0 : sd[t - 1];
  if (t < NSCAN) bsum[t] = excl;
}

__global__ void k_scan3(int* __restrict__ off, const int* __restrict__ bsum) {
  int t = threadIdx.x, b = blockIdx.x;
  int add = bsum[b];
  int base = b * SCAN_BLK + t * 4;
#pragma unroll
  for (int j = 0; j < 4; ++j) { int i = base + j; if (i < NSEG) off[i] += add; }
}

// Bumps off[key] itself (no cursor): post-scatter, off[key] = exclusive END of
// segment key; readers use beg(k) = (k==0 ? 0 : off[k-1]).
// Packs src(16b) | rel<<16 | (dst&15)<<19.
__global__ void k_scatter(const int* __restrict__ src, const int* __restrict__ dst,
                          const int* __restrict__ et, int* __restrict__ off,
                          int* __restrict__ srcPk) {
  int e = blockIdx.x * 256 + threadIdx.x;
  if (e >= N_EDGES) return;
  int d = dst[e], r = et[e];
  int key = d * N_REL + r;
  int pos = atomicAdd(&off[key], 1);
  srcPk[pos] = src[e] | (r << 16) | ((d & 15) << 19);
}

__global__ __launch_bounds__(512)
void k_fused(const unsigned int* __restrict__ xb,
             const int* __restrict__ off, const int* __restrict__ srcPk,
             const __hip_bfloat16* __restrict__ WcatT,
             const float* __restrict__ bias, const float* __restrict__ alpha,
             float* __restrict__ out) {
  __shared__ __hip_bfloat16 B16[DT * BSTRIDE];   // 37,120 B
  __shared__ float invc[DT * N_REL];
  int tid = threadIdx.x;
  int wave = tid >> 6, lane = tid & 63;
  int dstBase = blockIdx.x * DT;
  int seg0 = dstBase * N_REL;

  // ---- pre-pass: zero agg region; root rows (bf16); per-segment 1/cnt ----
  for (int i = tid; i < DT * 128; i += 512) {          // [DT][1024] shorts, b128
    int row = i >> 7, c = i & 127;
    *reinterpret_cast<int4*>(&B16[row * BSTRIDE + c * 8]) = make_int4(0, 0, 0, 0);
  }
  for (int i = tid; i < DT * 64; i += 512) {           // root region k=1024..1151
    int row = i >> 6, c = i & 63;
    *reinterpret_cast<unsigned int*>(&B16[row * BSTRIDE + 1024 + c * 2]) =
        xb[(size_t)(dstBase + row) * 64 + c];
  }
  if (tid < DT * N_REL) {
    int sg = seg0 + tid;
    int beg = (sg == 0) ? 0 : off[sg - 1];
    int c = off[sg] - beg;
    invc[tid] = (c > 0) ? 1.0f / (float)c : 0.0f;
  }
  int segw = seg0 + wave * 16;                          // wave owns rows 2w,2w+1
  int ebeg = (segw == 0) ? 0 : off[segw - 1];
  int eend = off[segw + 15];
  __syncthreads();

  // ---- edge walk: double-buffered 16-edge gather pipeline, reg accumulation ----
  float a0 = 0.f, a1 = 0.f;
  int curKey = -1;
  auto flush = [&]() {
    if (curKey >= 0) {
      int ld = curKey >> 3, r = curKey & 7;
      float iv = invc[(ld << 3) | r];
      __hip_bfloat16 b0 = __float2bfloat16(a0 * iv);
      __hip_bfloat16 b1 = __float2bfloat16(a1 * iv);
      unsigned int pk2 = (unsigned int)*(unsigned short*)&b0 |
                         ((unsigned int)*(unsigned short*)&b1 << 16);
      *reinterpret_cast<unsigned int*>(&B16[ld * BSTRIDE + r * CH + lane * 2]) = pk2;
    }
  };
  auto consume = [&](int base, const int* pk, const unsigned* u) {
#pragma unroll
    for (int j = 0; j < 16; ++j) {
      if (base + j < eend) {                            // wave-uniform (scalar)
        int key = pk[j] >> 16;
        if (key != curKey) { flush(); curKey = key; a0 = 0.f; a1 = 0.f; }
        a0 += __uint_as_float(u[j] << 16);
        a1 += __uint_as_float(u[j] & 0xffff0000u);
      }
    }
  };
  if (ebeg < eend) {
    int l16 = lane & 15;
    int last = eend - 1;
    int d0 = srcPk[min(ebeg + l16, last)];              // descs batch 0 (64B)
    int d1 = srcPk[min(ebeg + 16 + l16, last)];         // descs batch 1
    int pk0[16], pk1[16];                               // SGPRs via readlane
    unsigned u0[16], u1[16];                            // gather double buffer
#pragma unroll
    for (int j = 0; j < 16; ++j) pk0[j] = __builtin_amdgcn_readlane(d0, j);
#pragma unroll
    for (int j = 0; j < 16; ++j)
      if (ebeg + j < eend)                              // scalar guard: no over-issue
        u0[j] = xb[(size_t)(unsigned)(pk0[j] & 0xFFFF) * 64 + lane];
    for (int b = ebeg; b < eend; b += 32) {
      // issue batch b+16 while batch b is in flight / being consumed
#pragma unroll
      for (int j = 0; j < 16; ++j) pk1[j] = __builtin_amdgcn_readlane(d1, j);
#pragma unroll
      for (int j = 0; j < 16; ++j)
        if (b + 16 + j < eend)
          u1[j] = xb[(size_t)(unsigned)(pk1[j] & 0xFFFF) * 64 + lane];
      int d2 = srcPk[min(b + 32 + l16, last)];
      __builtin_amdgcn_sched_barrier(0);                // pin: all issues above
      consume(b, pk0, u0);
      // issue batch b+32 while batch b+16 is in flight / being consumed
#pragma unroll
      for (int j = 0; j < 16; ++j) pk0[j] = __builtin_amdgcn_readlane(d2, j);
#pragma unroll
      for (int j = 0; j < 16; ++j)
        if (b + 32 + j < eend)
          u0[j] = xb[(size_t)(unsigned)(pk0[j] & 0xFFFF) * 64 + lane];
      int d3 = srcPk[min(b + 48 + l16, last)];
      __builtin_amdgcn_sched_barrier(0);
      consume(b + 16, pk1, u1);
      d1 = d3;
    }
    flush();
  }
  __syncthreads();

  // ---- phase B: D[16x16] per wave over K=1152; wave w -> cols [16w,16w+16) ----
  int r16 = lane & 15, g = lane >> 4;
  f32x4 acc = {0.f, 0.f, 0.f, 0.f};
  const short* Wt = reinterpret_cast<const short*>(WcatT) + (size_t)(wave * 16 + r16) * KTOT;
  const short* Arow = reinterpret_cast<const short*>(B16) + r16 * BSTRIDE;
  for (int kk = 0; kk < KTOT / 32; ++kk) {
    int kb = kk * 32 + g * 8;
    bf16x8 af = *reinterpret_cast<const bf16x8*>(Arow + kb);
    bf16x8 bw = *reinterpret_cast<const bf16x8*>(Wt + kb);
    acc = __builtin_amdgcn_mfma_f32_16x16x32_bf16(af, bw, acc, 0, 0, 0);
  }

  int col = wave * 16 + r16;
  float bi = bias[col], al = alpha[col];
#pragma unroll
  for (int rg = 0; rg < 4; ++rg) {
    int row = g * 4 + rg;
    float v = acc[rg] + bi;
    v = (v >= 0.f) ? v : al * v;
    out[(size_t)(dstBase + row) * CH + col] = v;
  }
}

extern "C" void kernel_launch(void* const* d_in, const int* in_sizes, int n_in,
                              void* d_out, int out_size, void* d_ws, size_t ws_size,
                              hipStream_t stream) {
  const float* x     = (const float*)d_in[0];
  const int*   ei    = (const int*)d_in[1];
  const int*   etype = (const int*)d_in[2];
  const float* basis = (const float*)d_in[3];
  const float* comp  = (const float*)d_in[4];
  const float* root  = (const float*)d_in[5];
  const float* bias  = (const float*)d_in[6];
  const float* alpha = (const float*)d_in[7];
  const int* src = ei;
  const int* dst = ei + N_EDGES;
  float* out = (float*)d_out;

  char* ws = (char*)d_ws;
  size_t p = 0;
  auto alloc = [&](size_t bytes) {
    void* q = ws + p;
    p = (p + bytes + 255) & ~(size_t)255;
    return q;
  };
  __hip_bfloat16* WcatT = (__hip_bfloat16*)alloc((size_t)CH * KTOT * sizeof(__hip_bfloat16));
  int* off    = (int*)alloc((size_t)NSEG * sizeof(int));
  int* hist   = (int*)alloc((size_t)NSEG * sizeof(int));
  int* bsum   = (int*)alloc((size_t)NSCAN * sizeof(int));
  int* srcPk  = (int*)alloc((size_t)N_EDGES * sizeof(int));
  unsigned int* xb = (unsigned int*)alloc((size_t)N_NODES * CH / 2 * sizeof(unsigned int));

  hipMemsetAsync(hist, 0, (size_t)NSEG * sizeof(int), stream);
  k_prep<<<WBLK + N_NODES * CH / 4 / 256, 256, 0, stream>>>(basis, comp, root, WcatT, x, xb);
  k_hist<<<(N_EDGES + 255) / 256, 256, 0, stream>>>(dst, etype, hist);
  k_scan1<<<NSCAN, 256, 0, stream>>>(hist, off, bsum);
  k_scan2<<<1, 512, 0, stream>>>(bsum);
  k_scan3<<<NSCAN, 256, 0, stream>>>(off, bsum);
  k_scatter<<<(N_EDGES + 255) / 256, 256, 0, stream>>>(src, dst, etype, off, srcPk);
  k_fused<<<N_NODES / DT, 512, 0, stream>>>(xb, off, srcPk, WcatT, bias, alpha, out);
}